// Round 11
// baseline (382.171 us; speedup 1.0000x reference)
//
#include <hip/hip_runtime.h>
#include <hip/hip_bf16.h>

#define TQ 2048
#define HIDDEN 1024
#define NB 4
#define NH 16
#define DH 64
#define BHN (NB*NH)   // 64
#define LOG2E 1.44269504f

typedef __attribute__((ext_vector_type(4))) float f32x4;
typedef __attribute__((ext_vector_type(8))) short s16x8;

#if __has_builtin(__builtin_amdgcn_exp2f)
#define EXP2(x) __builtin_amdgcn_exp2f(x)
#else
#define EXP2(x) exp2f(x)
#endif

__device__ inline unsigned short f2bf(float f) {
    union { float f; unsigned int u; } x; x.f = f;
    unsigned int r = x.u + 0x7fffu + ((x.u >> 16) & 1u);
    return (unsigned short)(r >> 16);
}

__device__ inline unsigned int pkbf(float a, float b) {
    __hip_bfloat162 h = __float22bfloat162_rn(make_float2(a, b));
    return *reinterpret_cast<unsigned int*>(&h);
}

union PBU { uint4 u4; s16x8 v; };

// async global->LDS, 16B per lane; lds dst must be wave-uniform base
#define GLL16(gsrc, ldst) \
    __builtin_amdgcn_global_load_lds( \
        (const __attribute__((address_space(1))) unsigned int*)(gsrc), \
        (__attribute__((address_space(3))) unsigned int*)(ldst), 16, 0, 0)

// ---------------------------------------------------------------------------
// mask prep: maskAndB ushort [4][2048] in pb-slot-PERMUTED order:
// 0xFFFF (keep) / 0x0000 (masked). AND-ed against packed P bf16 pairs.
// ---------------------------------------------------------------------------
__global__ __launch_bounds__(256) void maskprep(const int* __restrict__ pad,
                                                unsigned short* __restrict__ maskAndB) {
    int p = blockIdx.x * 256 + threadIdx.x;   // 0..8191
    int r = p >> 11, off = p & 2047;
    int o6 = off & 63;
    int ks = o6 >> 5, k32 = o6 & 31;
    int lg = k32 >> 3, j = k32 & 7;
    int key = (off & ~63) | (ks * 32 + ((j >> 2) << 4) + (lg << 2) + (j & 3));
    maskAndB[p] = pad[r * 2048 + key] ? (unsigned short)0 : (unsigned short)0xFFFF;
}

// ---------------------------------------------------------------------------
// Weight transpose+convert: Wt[n][k] = bf16(W[k][n]); 4 weights via blockIdx.z
// ---------------------------------------------------------------------------
__global__ __launch_bounds__(256) void wt_kernel(const float* W0, const float* W1,
                                                 const float* W2, const float* W3,
                                                 unsigned short* Wt) {
    const float* W = (blockIdx.z == 0) ? W0 : (blockIdx.z == 1) ? W1
                    : (blockIdx.z == 2) ? W2 : W3;
    unsigned short* out = Wt + (size_t)blockIdx.z * HIDDEN * HIDDEN;
    __shared__ float tile[64][68];
    int t = threadIdx.x;
    int k0 = blockIdx.y * 64, n0 = blockIdx.x * 64;
#pragma unroll
    for (int i = 0; i < 4; i++) {
        int r = (t >> 4) + i * 16;
        int c = (t & 15) * 4;
        float4 v = *(const float4*)(W + (size_t)(k0 + r) * HIDDEN + n0 + c);
        tile[r][c] = v.x; tile[r][c+1] = v.y; tile[r][c+2] = v.z; tile[r][c+3] = v.w;
    }
    __syncthreads();
#pragma unroll
    for (int i = 0; i < 4; i++) {
        int n = (t >> 4) + i * 16;
        int kc = (t & 15) * 4;
        ushort4 o;
        o.x = f2bf(tile[kc+0][n]); o.y = f2bf(tile[kc+1][n]);
        o.z = f2bf(tile[kc+2][n]); o.w = f2bf(tile[kc+3][n]);
        *(ushort4*)(out + (size_t)(n0 + n) * HIDDEN + k0 + kc) = o;
    }
}

// ---------------------------------------------------------------------------
// Projection GEMM (R8 structure): A f32 [8192][1024] x Wt bf16 [n][k] n-major.
// 128x128 tile, BK=32, grid (8,64). A staged f32 via global_load_lds with
// pre-swizzled source (slot^(row&7)), swizzled read + cvt_pk on fragment read.
// B bf16, slot^(row&3). XCD-chunked tile swizzle.
// vt=0: out bf16 head-split [B*H][T][D], scaled
// vt=1: out bf16 head-split transposed [B*H][D][T], token index PERMUTED
//       within 32 (pb-slot order) so attention reads V-frags directly.
// ---------------------------------------------------------------------------
__global__ __launch_bounds__(256) void gemm_proj(const float* __restrict__ A,
                                                 const unsigned short* __restrict__ Bt,
                                                 unsigned short* __restrict__ outb,
                                                 float scale, int vt) {
    __shared__ alignas(16) float As[128 * 32];            // 16 KB
    __shared__ alignas(16) unsigned short Bs[128 * 32];   // 8 KB
    const int t = threadIdx.x;
    const int wave = t >> 6, lane = t & 63;
    const int wr = wave >> 1, wc = wave & 1;
    const int lr = lane & 15, lg = lane >> 4;
    const int linear = blockIdx.x + 8 * blockIdx.y;          // 0..511
    const int tile = ((linear & 7) << 6) | (linear >> 3);
    const int m0 = (tile >> 3) * 128, n0 = (tile & 7) * 128;

    size_t gA[4];
#pragma unroll
    for (int i = 0; i < 4; i++) {
        int f = i * 256 + t;
        int row = f >> 3, sg = (f & 7) ^ (row & 7);
        gA[i] = (size_t)(m0 + row) * HIDDEN + sg * 4;
    }
    size_t gB[2];
#pragma unroll
    for (int i = 0; i < 2; i++) {
        int f = i * 256 + t;
        int row = f >> 2, sg = (f & 3) ^ (row & 3);
        gB[i] = (size_t)(n0 + row) * HIDDEN + sg * 8;
    }
    float* lA0 = &As[(size_t)(0 * 256 + wave * 64) * 4];
    float* lA1 = &As[(size_t)(1 * 256 + wave * 64) * 4];
    float* lA2 = &As[(size_t)(2 * 256 + wave * 64) * 4];
    float* lA3 = &As[(size_t)(3 * 256 + wave * 64) * 4];
    unsigned short* lB0 = &Bs[(size_t)(0 * 256 + wave * 64) * 8];
    unsigned short* lB1 = &Bs[(size_t)(1 * 256 + wave * 64) * 8];

    f32x4 acc[4][4] = {};

    for (int k0 = 0; k0 < HIDDEN; k0 += 32) {
        __syncthreads();
        GLL16(A + gA[0] + k0, lA0);
        GLL16(A + gA[1] + k0, lA1);
        GLL16(A + gA[2] + k0, lA2);
        GLL16(A + gA[3] + k0, lA3);
        GLL16(Bt + gB[0] + k0, lB0);
        GLL16(Bt + gB[1] + k0, lB1);
        __syncthreads();
        s16x8 af[4], bfr[4];
#pragma unroll
        for (int mi = 0; mi < 4; mi++) {
            int row = wr * 64 + mi * 16 + lr;
            int s0 = (lg * 2) ^ (row & 7), s1 = (lg * 2 + 1) ^ (row & 7);
            float4 a0 = *(const float4*)(&As[row * 32 + s0 * 4]);
            float4 a1 = *(const float4*)(&As[row * 32 + s1 * 4]);
            PBU u;
            u.u4.x = pkbf(a0.x, a0.y); u.u4.y = pkbf(a0.z, a0.w);
            u.u4.z = pkbf(a1.x, a1.y); u.u4.w = pkbf(a1.z, a1.w);
            af[mi] = u.v;
        }
#pragma unroll
        for (int ni = 0; ni < 4; ni++) {
            int row = wc * 64 + ni * 16 + lr;
            int s = lg ^ (row & 3);
            bfr[ni] = *(const s16x8*)(&Bs[row * 32 + s * 8]);
        }
#pragma unroll
        for (int mi = 0; mi < 4; mi++)
#pragma unroll
            for (int ni = 0; ni < 4; ni++)
                acc[mi][ni] = __builtin_amdgcn_mfma_f32_16x16x32_bf16(af[mi], bfr[ni], acc[mi][ni], 0, 0, 0);
    }

    if (vt == 0) {
#pragma unroll
        for (int mi = 0; mi < 4; mi++)
#pragma unroll
            for (int ni = 0; ni < 4; ni++)
#pragma unroll
                for (int j = 0; j < 4; j++) {
                    int m = m0 + wr * 64 + mi * 16 + lg * 4 + j;
                    int n = n0 + wc * 64 + ni * 16 + lr;
                    int b = m >> 11, tt = m & (TQ - 1);
                    int h = n >> 6, d = n & 63;
                    outb[((size_t)(b * NH + h) * TQ + tt) * DH + d] = f2bf(acc[mi][ni][j] * scale);
                }
    } else {
#pragma unroll
        for (int mi = 0; mi < 4; mi++)
#pragma unroll
            for (int ni = 0; ni < 4; ni++) {
                int m = m0 + wr * 64 + mi * 16 + lg * 4;
                int n = n0 + wc * 64 + ni * 16 + lr;
                int b = m >> 11, tt = m & (TQ - 1);
                int h = n >> 6, d = n & 63;
                // pb-slot permutation of token index within its 32-group:
                // s = ((k>>2)&3)*8 + ((k>>4)&1)*4 + (k&3); here k&3==0, j adds 0..3
                int ttp = (tt & ~31) | (lg << 3) | ((mi & 1) << 2);
                ushort4 pk;
                pk.x = f2bf(acc[mi][ni][0] * scale);
                pk.y = f2bf(acc[mi][ni][1] * scale);
                pk.z = f2bf(acc[mi][ni][2] * scale);
                pk.w = f2bf(acc[mi][ni][3] * scale);
                *(ushort4*)(outb + ((size_t)(b * NH + h) * DH + d) * TQ + ttp) = pk;
            }
    }
}

// ---------------------------------------------------------------------------
// Final GEMM (R8 structure): A bf16 [8192][1024] x Wt bf16 -> out f32.
// 128x128 tile, grid (8,64), 4-slot XOR swizzle, XCD-chunked tile swizzle.
// ---------------------------------------------------------------------------
__global__ __launch_bounds__(256) void gemm_out(const unsigned short* __restrict__ A,
                                                const unsigned short* __restrict__ Bt,
                                                float* __restrict__ out) {
    __shared__ alignas(16) unsigned short As[128 * 32];
    __shared__ alignas(16) unsigned short Bs[128 * 32];
    const int t = threadIdx.x;
    const int wave = t >> 6, lane = t & 63;
    const int wr = wave >> 1, wc = wave & 1;
    const int lr = lane & 15, lg = lane >> 4;
    const int linear = blockIdx.x + 8 * blockIdx.y;
    const int tile = ((linear & 7) << 6) | (linear >> 3);
    const int m0 = (tile >> 3) * 128, n0 = (tile & 7) * 128;

    size_t gA[2], gB[2];
#pragma unroll
    for (int i = 0; i < 2; i++) {
        int f = i * 256 + t;
        int row = f >> 2, sg = (f & 3) ^ (row & 3);
        gA[i] = (size_t)(m0 + row) * HIDDEN + sg * 8;
        gB[i] = (size_t)(n0 + row) * HIDDEN + sg * 8;
    }
    unsigned short* lA0 = &As[(size_t)(0 * 256 + wave * 64) * 8];
    unsigned short* lA1 = &As[(size_t)(1 * 256 + wave * 64) * 8];
    unsigned short* lB0 = &Bs[(size_t)(0 * 256 + wave * 64) * 8];
    unsigned short* lB1 = &Bs[(size_t)(1 * 256 + wave * 64) * 8];

    f32x4 acc[4][4] = {};

    for (int k0 = 0; k0 < HIDDEN; k0 += 32) {
        __syncthreads();
        GLL16(A + gA[0] + k0, lA0);
        GLL16(A + gA[1] + k0, lA1);
        GLL16(Bt + gB[0] + k0, lB0);
        GLL16(Bt + gB[1] + k0, lB1);
        __syncthreads();
        s16x8 af[4], bfr[4];
#pragma unroll
        for (int mi = 0; mi < 4; mi++) {
            int row = wr * 64 + mi * 16 + lr;
            int s = lg ^ (row & 3);
            af[mi] = *(const s16x8*)(&As[row * 32 + s * 8]);
        }
#pragma unroll
        for (int ni = 0; ni < 4; ni++) {
            int row = wc * 64 + ni * 16 + lr;
            int s = lg ^ (row & 3);
            bfr[ni] = *(const s16x8*)(&Bs[row * 32 + s * 8]);
        }
#pragma unroll
        for (int mi = 0; mi < 4; mi++)
#pragma unroll
            for (int ni = 0; ni < 4; ni++)
                acc[mi][ni] = __builtin_amdgcn_mfma_f32_16x16x32_bf16(af[mi], bfr[ni], acc[mi][ni], 0, 0, 0);
    }
#pragma unroll
    for (int mi = 0; mi < 4; mi++)
#pragma unroll
        for (int ni = 0; ni < 4; ni++)
#pragma unroll
            for (int j = 0; j < 4; j++) {
                int m = m0 + wr * 64 + mi * 16 + lg * 4 + j;
                int n = n0 + wc * 64 + ni * 16 + lr;
                out[(size_t)m * HIDDEN + n] = acc[mi][ni][j];
            }
}

// ---------------------------------------------------------------------------
// Flash attention v9: NO LDS, NO BARRIERS. K/V frags read directly from
// global (L2-resident per XCD: 8 bh x 512KB = 4MB; L1 serves intra-block
// reuse across the 8 waves). 8 waves x 32 q-rows (u=2), grid (8,64)=512.
// Fixed-shift softmax; V comes pre-permuted from proj (pb-slot order);
// mask via P-AND; ones-MFMA denominator; setprio around MFMA clusters.
// ---------------------------------------------------------------------------
__global__ __launch_bounds__(512, 4) void attn_kernel(
        const unsigned short* __restrict__ QP,
        const unsigned short* __restrict__ KP,
        const unsigned short* __restrict__ VT,
        const unsigned short* __restrict__ maskAndB,
        unsigned short* __restrict__ AO) {
    const int t = threadIdx.x, wave = t >> 6, lane = t & 63;
    const int lr = lane & 15, lg = lane >> 4;
    // XCD swizzle: linear = c + 8j -> bh = c*8 + (j&7), qb = j>>3
    const int linear = blockIdx.x + 8 * blockIdx.y;          // 0..511
    const int bh = ((linear & 7) << 3) | ((linear >> 3) & 7);
    const int qb = linear >> 6;                               // 0..7
    const int q0 = qb * 256 + wave * 32;
    const unsigned short* Qb = QP + (size_t)bh * TQ * DH;
    const unsigned short* Kb = KP + (size_t)bh * TQ * DH;
    const unsigned short* Vb = VT + (size_t)bh * DH * TQ;
    const unsigned short* mrow = maskAndB + (bh & (NB - 1)) * TQ;

    const short ob = (short)0x3F80;                    // bf16 1.0
    const s16x8 ones = {ob, ob, ob, ob, ob, ob, ob, ob};

    s16x8 qf[2][2];
#pragma unroll
    for (int u = 0; u < 2; u++)
#pragma unroll
        for (int h = 0; h < 2; h++)
            qf[u][h] = *(const s16x8*)(Qb + (size_t)(q0 + u * 16 + lr) * DH + h * 32 + lg * 8);

    // per-thread fragment base pointers
    const unsigned short* kB[4];
#pragma unroll
    for (int ni = 0; ni < 4; ni++)
        kB[ni] = Kb + (size_t)(ni * 16 + lr) * DH + lg * 8;
    const unsigned short* vB[4];
#pragma unroll
    for (int di = 0; di < 4; di++)
        vB[di] = Vb + (size_t)(di * 16 + lr) * TQ + lg * 8;
    const unsigned short* mB = mrow + lg * 8;

    f32x4 o[2][4] = {};
    f32x4 osum[2] = {};

    const int NT = TQ / 64;
    for (int kt = 0; kt < NT; kt++) {
        const int kOff = kt * 64 * DH;   // 64 rows ahead in K
        const int vOff = kt * 64;        // 64 cols ahead in VT
        uint4 ma0 = *(const uint4*)(mB + vOff);
        uint4 ma1 = *(const uint4*)(mB + vOff + 32);

        // S^T: z[u][ni][r], q=lr, k=ni*16+lg*4+r
        f32x4 z[2][4] = {};
        __builtin_amdgcn_s_setprio(1);
#pragma unroll
        for (int ni = 0; ni < 4; ni++) {
            s16x8 kf0 = *(const s16x8*)(kB[ni] + kOff);
            s16x8 kf1 = *(const s16x8*)(kB[ni] + kOff + 32);
            z[0][ni] = __builtin_amdgcn_mfma_f32_16x16x32_bf16(kf0, qf[0][0], z[0][ni], 0, 0, 0);
            z[0][ni] = __builtin_amdgcn_mfma_f32_16x16x32_bf16(kf1, qf[0][1], z[0][ni], 0, 0, 0);
            z[1][ni] = __builtin_amdgcn_mfma_f32_16x16x32_bf16(kf0, qf[1][0], z[1][ni], 0, 0, 0);
            z[1][ni] = __builtin_amdgcn_mfma_f32_16x16x32_bf16(kf1, qf[1][1], z[1][ni], 0, 0, 0);
        }
        __builtin_amdgcn_s_setprio(0);

        // P = exp2(z), pack in-lane (k-slot perm), AND mask
        PBU pb[2][2];
#pragma unroll
        for (int u = 0; u < 2; u++) {
#pragma unroll
            for (int ni = 0; ni < 4; ni++)
#pragma unroll
                for (int r = 0; r < 4; r++)
                    z[u][ni][r] = EXP2(z[u][ni][r]);
#pragma unroll
            for (int ks = 0; ks < 2; ks++) {
                pb[u][ks].u4.x = pkbf(z[u][2 * ks][0], z[u][2 * ks][1]);
                pb[u][ks].u4.y = pkbf(z[u][2 * ks][2], z[u][2 * ks][3]);
                pb[u][ks].u4.z = pkbf(z[u][2 * ks + 1][0], z[u][2 * ks + 1][1]);
                pb[u][ks].u4.w = pkbf(z[u][2 * ks + 1][2], z[u][2 * ks + 1][3]);
            }
            pb[u][0].u4.x &= ma0.x; pb[u][0].u4.y &= ma0.y;
            pb[u][0].u4.z &= ma0.z; pb[u][0].u4.w &= ma0.w;
            pb[u][1].u4.x &= ma1.x; pb[u][1].u4.y &= ma1.y;
            pb[u][1].u4.z &= ma1.z; pb[u][1].u4.w &= ma1.w;
        }

        // O^T += V^T x P^T ; denominator via const-ones MFMA
        __builtin_amdgcn_s_setprio(1);
#pragma unroll
        for (int di = 0; di < 4; di++) {
            s16x8 vf0 = *(const s16x8*)(vB[di] + vOff);
            s16x8 vf1 = *(const s16x8*)(vB[di] + vOff + 32);
            o[0][di] = __builtin_amdgcn_mfma_f32_16x16x32_bf16(vf0, pb[0][0].v, o[0][di], 0, 0, 0);
            o[0][di] = __builtin_amdgcn_mfma_f32_16x16x32_bf16(vf1, pb[0][1].v, o[0][di], 0, 0, 0);
            o[1][di] = __builtin_amdgcn_mfma_f32_16x16x32_bf16(vf0, pb[1][0].v, o[1][di], 0, 0, 0);
            o[1][di] = __builtin_amdgcn_mfma_f32_16x16x32_bf16(vf1, pb[1][1].v, o[1][di], 0, 0, 0);
        }
#pragma unroll
        for (int u = 0; u < 2; u++) {
            osum[u] = __builtin_amdgcn_mfma_f32_16x16x32_bf16(ones, pb[u][0].v, osum[u], 0, 0, 0);
            osum[u] = __builtin_amdgcn_mfma_f32_16x16x32_bf16(ones, pb[u][1].v, osum[u], 0, 0, 0);
        }
        __builtin_amdgcn_s_setprio(0);
    }

    // epilogue: lane holds q=lr; osum[u][*] = denominator for that q
    const int b = bh >> 4, h = bh & 15;
#pragma unroll
    for (int u = 0; u < 2; u++) {
        float inv = 1.f / osum[u][0];
        int tt = q0 + u * 16 + lr;
#pragma unroll
        for (int di = 0; di < 4; di++) {
            uint2 w;
            w.x = pkbf(o[u][di][0] * inv, o[u][di][1] * inv);
            w.y = pkbf(o[u][di][2] * inv, o[u][di][3] * inv);
            *(uint2*)(AO + (size_t)(b * TQ + tt) * HIDDEN + h * 64 + di * 16 + lg * 4) = w;
        }
    }
}

// ---------------------------------------------------------------------------
extern "C" void kernel_launch(void* const* d_in, const int* in_sizes, int n_in,
                              void* d_out, int out_size, void* d_ws, size_t ws_size,
                              hipStream_t stream) {
    const float* q  = (const float*)d_in[0];
    const float* k  = (const float*)d_in[1];
    const float* v  = (const float*)d_in[2];
    const int* pad  = (const int*)d_in[3];
    const float* Wq = (const float*)d_in[4];
    const float* Wk = (const float*)d_in[5];
    const float* Wv = (const float*)d_in[6];
    const float* Wo = (const float*)d_in[7];
    float* out = (float*)d_out;

    // ws (bf16 elems): Wt 4M | AO 8.39M | QP | KP | VT | maskAndB
    unsigned short* ws = (unsigned short*)d_ws;
    unsigned short* Wt = ws;
    unsigned short* AO = ws + (size_t)4 * 1024 * 1024;
    unsigned short* QP = AO + (size_t)BHN * TQ * DH;
    unsigned short* KP = QP + (size_t)BHN * TQ * DH;
    unsigned short* VTb = KP + (size_t)BHN * TQ * DH;
    unsigned short* maskAndB = VTb + (size_t)BHN * TQ * DH;
    (void)ws_size; (void)in_sizes; (void)n_in; (void)out_size;

    dim3 b256(256);
    const dim3 gGemm(8, 64);
    maskprep<<<dim3(NB * TQ / 256), b256, 0, stream>>>(pad, maskAndB);
    wt_kernel<<<dim3(16, 16, 4), b256, 0, stream>>>(Wq, Wk, Wv, Wo, Wt);
    gemm_proj<<<gGemm, b256, 0, stream>>>(q, Wt + (size_t)0 * 1024 * 1024, QP, 0.125f * LOG2E, 0);
    gemm_proj<<<gGemm, b256, 0, stream>>>(k, Wt + (size_t)1 * 1024 * 1024, KP, 1.0f, 0);
    gemm_proj<<<gGemm, b256, 0, stream>>>(v, Wt + (size_t)2 * 1024 * 1024, VTb, 1.0f, 1);
    attn_kernel<<<dim3(8, 64), dim3(512), 0, stream>>>(QP, KP, VTb, maskAndB, AO);
    gemm_out<<<gGemm, b256, 0, stream>>>(AO, Wt + (size_t)3 * 1024 * 1024, out);
}

// Round 12
// 203.814 us; speedup vs baseline: 1.8751x; 1.8751x over previous
//
#include <hip/hip_runtime.h>
#include <hip/hip_bf16.h>

#define TQ 2048
#define HIDDEN 1024
#define NB 4
#define NH 16
#define DH 64
#define BHN (NB*NH)   // 64
#define LOG2E 1.44269504f

typedef __attribute__((ext_vector_type(4))) float f32x4;
typedef __attribute__((ext_vector_type(8))) short s16x8;

#if __has_builtin(__builtin_amdgcn_exp2f)
#define EXP2(x) __builtin_amdgcn_exp2f(x)
#else
#define EXP2(x) exp2f(x)
#endif

__device__ inline unsigned short f2bf(float f) {
    union { float f; unsigned int u; } x; x.f = f;
    unsigned int r = x.u + 0x7fffu + ((x.u >> 16) & 1u);
    return (unsigned short)(r >> 16);
}

__device__ inline unsigned int pkbf(float a, float b) {
    __hip_bfloat162 h = __float22bfloat162_rn(make_float2(a, b));
    return *reinterpret_cast<unsigned int*>(&h);
}

union PBU { uint4 u4; s16x8 v; };

// async global->LDS, 16B per lane; lds dst must be wave-uniform base
#define GLL16(gsrc, ldst) \
    __builtin_amdgcn_global_load_lds( \
        (const __attribute__((address_space(1))) unsigned int*)(gsrc), \
        (__attribute__((address_space(3))) unsigned int*)(ldst), 16, 0, 0)

// ---------------------------------------------------------------------------
// mask prep: maskAndB ushort [4][2048] in pb-slot-PERMUTED order:
// 0xFFFF (keep) / 0x0000 (masked). AND-ed against packed P bf16 pairs.
// ---------------------------------------------------------------------------
__global__ __launch_bounds__(256) void maskprep(const int* __restrict__ pad,
                                                unsigned short* __restrict__ maskAndB) {
    int p = blockIdx.x * 256 + threadIdx.x;   // 0..8191
    int r = p >> 11, off = p & 2047;
    int o6 = off & 63;
    int ks = o6 >> 5, k32 = o6 & 31;
    int lg = k32 >> 3, j = k32 & 7;
    int key = (off & ~63) | (ks * 32 + ((j >> 2) << 4) + (lg << 2) + (j & 3));
    maskAndB[p] = pad[r * 2048 + key] ? (unsigned short)0 : (unsigned short)0xFFFF;
}

// ---------------------------------------------------------------------------
// Weight transpose+convert: Wt[n][k] = bf16(W[k][n]); 4 weights via blockIdx.z
// ---------------------------------------------------------------------------
__global__ __launch_bounds__(256) void wt_kernel(const float* W0, const float* W1,
                                                 const float* W2, const float* W3,
                                                 unsigned short* Wt) {
    const float* W = (blockIdx.z == 0) ? W0 : (blockIdx.z == 1) ? W1
                    : (blockIdx.z == 2) ? W2 : W3;
    unsigned short* out = Wt + (size_t)blockIdx.z * HIDDEN * HIDDEN;
    __shared__ float tile[64][68];
    int t = threadIdx.x;
    int k0 = blockIdx.y * 64, n0 = blockIdx.x * 64;
#pragma unroll
    for (int i = 0; i < 4; i++) {
        int r = (t >> 4) + i * 16;
        int c = (t & 15) * 4;
        float4 v = *(const float4*)(W + (size_t)(k0 + r) * HIDDEN + n0 + c);
        tile[r][c] = v.x; tile[r][c+1] = v.y; tile[r][c+2] = v.z; tile[r][c+3] = v.w;
    }
    __syncthreads();
#pragma unroll
    for (int i = 0; i < 4; i++) {
        int n = (t >> 4) + i * 16;
        int kc = (t & 15) * 4;
        ushort4 o;
        o.x = f2bf(tile[kc+0][n]); o.y = f2bf(tile[kc+1][n]);
        o.z = f2bf(tile[kc+2][n]); o.w = f2bf(tile[kc+3][n]);
        *(ushort4*)(out + (size_t)(n0 + n) * HIDDEN + k0 + kc) = o;
    }
}

// ---------------------------------------------------------------------------
// Projection GEMM, BK=64: A f32 [8192][1024] x Wt bf16 [n][k] n-major.
// 128x128 tile, grid (8,64). A staged f32 (32KB) via global_load_lds with
// pre-swizzled source (16 slots/row, slot^(row&15)); B bf16 (16KB,
// 8 slots/row, slot^(row&7)). Fragments cvt f32->bf16 on read.
// 32 MFMA per barrier-pair per wave (2 k-subtiles). XCD-chunked tile swizzle.
// vt=0: out bf16 head-split [B*H][T][D], scaled
// vt=1: out bf16 head-split transposed [B*H][D][T]
// ---------------------------------------------------------------------------
__global__ __launch_bounds__(256) void gemm_proj(const float* __restrict__ A,
                                                 const unsigned short* __restrict__ Bt,
                                                 unsigned short* __restrict__ outb,
                                                 float scale, int vt) {
    __shared__ alignas(16) float As[128 * 64];            // 32 KB
    __shared__ alignas(16) unsigned short Bs[128 * 64];   // 16 KB
    const int t = threadIdx.x;
    const int wave = t >> 6, lane = t & 63;
    const int wr = wave >> 1, wc = wave & 1;
    const int lr = lane & 15, lg = lane >> 4;
    const int linear = blockIdx.x + 8 * blockIdx.y;          // 0..511
    const int tile = ((linear & 7) << 6) | (linear >> 3);
    const int m0 = (tile >> 3) * 128, n0 = (tile & 7) * 128;

    // A: 128 rows x 64 f32 = 2048 16B-chunks (16/row); 8 per thread
    size_t gA[8];
#pragma unroll
    for (int i = 0; i < 8; i++) {
        int f = i * 256 + t;
        int row = f >> 4, sg = (f & 15) ^ (row & 15);
        gA[i] = (size_t)(m0 + row) * HIDDEN + sg * 4;
    }
    // B: 128 rows x 64 bf16 = 1024 16B-chunks (8/row); 4 per thread
    size_t gB[4];
#pragma unroll
    for (int i = 0; i < 4; i++) {
        int f = i * 256 + t;
        int row = f >> 3, sg = (f & 7) ^ (row & 7);
        gB[i] = (size_t)(n0 + row) * HIDDEN + sg * 8;
    }

    f32x4 acc[4][4] = {};

    for (int k0 = 0; k0 < HIDDEN; k0 += 64) {
        __syncthreads();
#pragma unroll
        for (int i = 0; i < 8; i++)
            GLL16(A + gA[i] + k0, &As[(size_t)(i * 256 + wave * 64) * 4]);
#pragma unroll
        for (int i = 0; i < 4; i++)
            GLL16(Bt + gB[i] + k0, &Bs[(size_t)(i * 256 + wave * 64) * 8]);
        __syncthreads();
#pragma unroll
        for (int q = 0; q < 2; q++) {
            s16x8 af[4], bfr[4];
#pragma unroll
            for (int mi = 0; mi < 4; mi++) {
                int row = wr * 64 + mi * 16 + lr;
                int s0 = (q * 8 + lg * 2) ^ (row & 15);
                int s1 = (q * 8 + lg * 2 + 1) ^ (row & 15);
                float4 a0 = *(const float4*)(&As[row * 64 + s0 * 4]);
                float4 a1 = *(const float4*)(&As[row * 64 + s1 * 4]);
                PBU u;
                u.u4.x = pkbf(a0.x, a0.y); u.u4.y = pkbf(a0.z, a0.w);
                u.u4.z = pkbf(a1.x, a1.y); u.u4.w = pkbf(a1.z, a1.w);
                af[mi] = u.v;
            }
#pragma unroll
            for (int ni = 0; ni < 4; ni++) {
                int row = wc * 64 + ni * 16 + lr;
                int s = (q * 4 + lg) ^ (row & 7);
                bfr[ni] = *(const s16x8*)(&Bs[row * 64 + s * 8]);
            }
#pragma unroll
            for (int mi = 0; mi < 4; mi++)
#pragma unroll
                for (int ni = 0; ni < 4; ni++)
                    acc[mi][ni] = __builtin_amdgcn_mfma_f32_16x16x32_bf16(af[mi], bfr[ni], acc[mi][ni], 0, 0, 0);
        }
    }

    if (vt == 0) {
#pragma unroll
        for (int mi = 0; mi < 4; mi++)
#pragma unroll
            for (int ni = 0; ni < 4; ni++)
#pragma unroll
                for (int j = 0; j < 4; j++) {
                    int m = m0 + wr * 64 + mi * 16 + lg * 4 + j;
                    int n = n0 + wc * 64 + ni * 16 + lr;
                    int b = m >> 11, tt = m & (TQ - 1);
                    int h = n >> 6, d = n & 63;
                    outb[((size_t)(b * NH + h) * TQ + tt) * DH + d] = f2bf(acc[mi][ni][j] * scale);
                }
    } else {
#pragma unroll
        for (int mi = 0; mi < 4; mi++)
#pragma unroll
            for (int ni = 0; ni < 4; ni++) {
                int m = m0 + wr * 64 + mi * 16 + lg * 4;
                int n = n0 + wc * 64 + ni * 16 + lr;
                int b = m >> 11, tt = m & (TQ - 1);
                int h = n >> 6, d = n & 63;
                ushort4 pk;
                pk.x = f2bf(acc[mi][ni][0] * scale);
                pk.y = f2bf(acc[mi][ni][1] * scale);
                pk.z = f2bf(acc[mi][ni][2] * scale);
                pk.w = f2bf(acc[mi][ni][3] * scale);
                *(ushort4*)(outb + ((size_t)(b * NH + h) * DH + d) * TQ + tt) = pk;
            }
    }
}

// ---------------------------------------------------------------------------
// Final GEMM, BK=64: A bf16 [8192][1024] (AO) x Wt bf16 -> out f32.
// 128x128 tile, grid (8,64); both tiles bf16 16KB (8 slots/row, XOR row&7).
// ---------------------------------------------------------------------------
__global__ __launch_bounds__(256) void gemm_out(const unsigned short* __restrict__ A,
                                                const unsigned short* __restrict__ Bt,
                                                float* __restrict__ out) {
    __shared__ alignas(16) unsigned short As[128 * 64];   // 16 KB
    __shared__ alignas(16) unsigned short Bs[128 * 64];   // 16 KB
    const int t = threadIdx.x;
    const int wave = t >> 6, lane = t & 63;
    const int wr = wave >> 1, wc = wave & 1;
    const int lr = lane & 15, lg = lane >> 4;
    const int linear = blockIdx.x + 8 * blockIdx.y;
    const int tile = ((linear & 7) << 6) | (linear >> 3);
    const int m0 = (tile >> 3) * 128, n0 = (tile & 7) * 128;

    size_t gA[4], gB[4];
#pragma unroll
    for (int i = 0; i < 4; i++) {
        int f = i * 256 + t;
        int row = f >> 3, sg = (f & 7) ^ (row & 7);
        gA[i] = (size_t)(m0 + row) * HIDDEN + sg * 8;
        gB[i] = (size_t)(n0 + row) * HIDDEN + sg * 8;
    }

    f32x4 acc[4][4] = {};

    for (int k0 = 0; k0 < HIDDEN; k0 += 64) {
        __syncthreads();
#pragma unroll
        for (int i = 0; i < 4; i++) {
            GLL16(A + gA[i] + k0, &As[(size_t)(i * 256 + wave * 64) * 8]);
            GLL16(Bt + gB[i] + k0, &Bs[(size_t)(i * 256 + wave * 64) * 8]);
        }
        __syncthreads();
#pragma unroll
        for (int q = 0; q < 2; q++) {
            s16x8 af[4], bfr[4];
#pragma unroll
            for (int mi = 0; mi < 4; mi++) {
                int row = wr * 64 + mi * 16 + lr;
                int s = (q * 4 + lg) ^ (row & 7);
                af[mi] = *(const s16x8*)(&As[row * 64 + s * 8]);
            }
#pragma unroll
            for (int ni = 0; ni < 4; ni++) {
                int row = wc * 64 + ni * 16 + lr;
                int s = (q * 4 + lg) ^ (row & 7);
                bfr[ni] = *(const s16x8*)(&Bs[row * 64 + s * 8]);
            }
#pragma unroll
            for (int mi = 0; mi < 4; mi++)
#pragma unroll
                for (int ni = 0; ni < 4; ni++)
                    acc[mi][ni] = __builtin_amdgcn_mfma_f32_16x16x32_bf16(af[mi], bfr[ni], acc[mi][ni], 0, 0, 0);
        }
    }
#pragma unroll
    for (int mi = 0; mi < 4; mi++)
#pragma unroll
        for (int ni = 0; ni < 4; ni++)
#pragma unroll
            for (int j = 0; j < 4; j++) {
                int m = m0 + wr * 64 + mi * 16 + lg * 4 + j;
                int n = n0 + wc * 64 + ni * 16 + lr;
                out[(size_t)m * HIDDEN + n] = acc[mi][ni][j];
            }
}

// ---------------------------------------------------------------------------
// Flash attention (R8-exact, measured 89.5 us): 8 waves x 32 q-rows, KV tiles
// 64 dbuf LDS, grid (8,64). Fixed-shift softmax (no max/rescale/cross-lane).
// XCD-chunked bh swizzle. Swapped QK (S^T, q=lane&15), in-lane P packing
// (k-slot perm), P-AND mask, ones-MFMA denominator.
// ---------------------------------------------------------------------------
__global__ __launch_bounds__(512, 4) void attn_kernel(
        const unsigned short* __restrict__ QP,
        const unsigned short* __restrict__ KP,
        const unsigned short* __restrict__ VT,
        const unsigned short* __restrict__ maskAndB,
        unsigned short* __restrict__ AO) {
    __shared__ alignas(16) unsigned short Ks[2][64 * 72];
    __shared__ alignas(16) unsigned short Vs[2][64 * 72];
    const int t = threadIdx.x, wave = t >> 6, lane = t & 63;
    const int lr = lane & 15, lg = lane >> 4;
    const int linear = blockIdx.x + 8 * blockIdx.y;          // 0..511
    const int bh = ((linear & 7) << 3) | ((linear >> 3) & 7);
    const int qb = linear >> 6;
    const int q0 = qb * 256 + wave * 32;
    const unsigned short* Qb = QP + (size_t)bh * TQ * DH;
    const unsigned short* Kb = KP + (size_t)bh * TQ * DH;
    const unsigned short* Vb = VT + (size_t)bh * DH * TQ;
    const unsigned short* mrow = maskAndB + (bh & (NB - 1)) * TQ;

    const short ob = (short)0x3F80;                    // bf16 1.0
    const s16x8 ones = {ob, ob, ob, ob, ob, ob, ob, ob};

    s16x8 qf[2][2];
#pragma unroll
    for (int u = 0; u < 2; u++)
#pragma unroll
        for (int h = 0; h < 2; h++)
            qf[u][h] = *(const s16x8*)(Qb + (size_t)(q0 + u * 16 + lr) * DH + h * 32 + lg * 8);

    const int srow = t >> 3, scol = (t & 7) * 8;
    const unsigned short* kA = Kb + srow * DH + scol;          // + kt*4096
    const unsigned short* vA = Vb + (size_t)srow * TQ + scol;  // + kt*64
    const int ksO = srow * 72 + scol;
    const int cc = t & 7;
    const int vg = ((cc & 4) << 1) + ((cc & 1) << 2) + ((cc >> 1) & 1);
    const int vO = srow * 72 + vg * 4;

    uint4 kr, vr;
#define LOAD_TILE(kt_) do { \
        kr = *(const uint4*)(kA + (size_t)(kt_) * 4096); \
        vr = *(const uint4*)(vA + (size_t)(kt_) * 64); \
    } while (0)
#define STORE_TILE(b_) do { \
        *(uint4*)(&Ks[b_][ksO]) = kr; \
        *(uint2*)(&Vs[b_][vO])     = make_uint2(vr.x, vr.y); \
        *(uint2*)(&Vs[b_][vO + 8]) = make_uint2(vr.z, vr.w); \
    } while (0)

    f32x4 o[2][4] = {};
    f32x4 osum[2] = {};

    LOAD_TILE(0);
    STORE_TILE(0);

    const int NT = TQ / 64;
    for (int kt = 0; kt < NT; kt++) {
        __syncthreads();
        const int cur = kt & 1;
        if (kt + 1 < NT) LOAD_TILE(kt + 1);
        uint4 ma0 = *(const uint4*)(mrow + kt * 64 + lg * 8);
        uint4 ma1 = *(const uint4*)(mrow + kt * 64 + 32 + lg * 8);

        // S^T: z[u][ni][r], q=lr, k=ni*16+lg*4+r
        f32x4 z[2][4] = {};
#pragma unroll
        for (int ni = 0; ni < 4; ni++) {
            s16x8 kf0 = *(const s16x8*)(&Ks[cur][(ni * 16 + lr) * 72 + lg * 8]);
            s16x8 kf1 = *(const s16x8*)(&Ks[cur][(ni * 16 + lr) * 72 + 32 + lg * 8]);
#pragma unroll
            for (int u = 0; u < 2; u++) {
                z[u][ni] = __builtin_amdgcn_mfma_f32_16x16x32_bf16(kf0, qf[u][0], z[u][ni], 0, 0, 0);
                z[u][ni] = __builtin_amdgcn_mfma_f32_16x16x32_bf16(kf1, qf[u][1], z[u][ni], 0, 0, 0);
            }
        }

        // P = exp2(z) (fixed-shift softmax), pack in-lane, AND mask
        PBU pb[2][2];
#pragma unroll
        for (int u = 0; u < 2; u++) {
#pragma unroll
            for (int ni = 0; ni < 4; ni++)
#pragma unroll
                for (int r = 0; r < 4; r++)
                    z[u][ni][r] = EXP2(z[u][ni][r]);
#pragma unroll
            for (int ks = 0; ks < 2; ks++) {
                pb[u][ks].u4.x = pkbf(z[u][2 * ks][0], z[u][2 * ks][1]);
                pb[u][ks].u4.y = pkbf(z[u][2 * ks][2], z[u][2 * ks][3]);
                pb[u][ks].u4.z = pkbf(z[u][2 * ks + 1][0], z[u][2 * ks + 1][1]);
                pb[u][ks].u4.w = pkbf(z[u][2 * ks + 1][2], z[u][2 * ks + 1][3]);
            }
            pb[u][0].u4.x &= ma0.x; pb[u][0].u4.y &= ma0.y;
            pb[u][0].u4.z &= ma0.z; pb[u][0].u4.w &= ma0.w;
            pb[u][1].u4.x &= ma1.x; pb[u][1].u4.y &= ma1.y;
            pb[u][1].u4.z &= ma1.z; pb[u][1].u4.w &= ma1.w;
        }

        // O^T += V^T x P^T ; denominator via const-ones MFMA (pb pre-masked)
#pragma unroll
        for (int di = 0; di < 4; di++)
#pragma unroll
            for (int ks = 0; ks < 2; ks++) {
                s16x8 vf = *(const s16x8*)(&Vs[cur][(di * 16 + lr) * 72 + ks * 32 + lg * 8]);
#pragma unroll
                for (int u = 0; u < 2; u++)
                    o[u][di] = __builtin_amdgcn_mfma_f32_16x16x32_bf16(vf, pb[u][ks].v, o[u][di], 0, 0, 0);
            }
#pragma unroll
        for (int u = 0; u < 2; u++) {
            osum[u] = __builtin_amdgcn_mfma_f32_16x16x32_bf16(ones, pb[u][0].v, osum[u], 0, 0, 0);
            osum[u] = __builtin_amdgcn_mfma_f32_16x16x32_bf16(ones, pb[u][1].v, osum[u], 0, 0, 0);
        }

        if (kt + 1 < NT) STORE_TILE((kt + 1) & 1);
    }

    // epilogue: lane holds q=lr; osum[u][*] = denominator for that q
    const int b = bh >> 4, h = bh & 15;
#pragma unroll
    for (int u = 0; u < 2; u++) {
        float inv = 1.f / osum[u][0];
        int tt = q0 + u * 16 + lr;
#pragma unroll
        for (int di = 0; di < 4; di++) {
            uint2 w;
            w.x = pkbf(o[u][di][0] * inv, o[u][di][1] * inv);
            w.y = pkbf(o[u][di][2] * inv, o[u][di][3] * inv);
            *(uint2*)(AO + (size_t)(b * TQ + tt) * HIDDEN + h * 64 + di * 16 + lg * 4) = w;
        }
    }
#undef LOAD_TILE
#undef STORE_TILE
}

// ---------------------------------------------------------------------------
extern "C" void kernel_launch(void* const* d_in, const int* in_sizes, int n_in,
                              void* d_out, int out_size, void* d_ws, size_t ws_size,
                              hipStream_t stream) {
    const float* q  = (const float*)d_in[0];
    const float* k  = (const float*)d_in[1];
    const float* v  = (const float*)d_in[2];
    const int* pad  = (const int*)d_in[3];
    const float* Wq = (const float*)d_in[4];
    const float* Wk = (const float*)d_in[5];
    const float* Wv = (const float*)d_in[6];
    const float* Wo = (const float*)d_in[7];
    float* out = (float*)d_out;

    // ws (bf16 elems): Wt 4M | AO 8.39M | QP | KP | VT | maskAndB
    unsigned short* ws = (unsigned short*)d_ws;
    unsigned short* Wt = ws;
    unsigned short* AO = ws + (size_t)4 * 1024 * 1024;
    unsigned short* QP = AO + (size_t)BHN * TQ * DH;
    unsigned short* KP = QP + (size_t)BHN * TQ * DH;
    unsigned short* VTb = KP + (size_t)BHN * TQ * DH;
    unsigned short* maskAndB = VTb + (size_t)BHN * TQ * DH;
    (void)ws_size; (void)in_sizes; (void)n_in; (void)out_size;

    dim3 b256(256);
    const dim3 gGemm(8, 64);
    maskprep<<<dim3(NB * TQ / 256), b256, 0, stream>>>(pad, maskAndB);
    wt_kernel<<<dim3(16, 16, 4), b256, 0, stream>>>(Wq, Wk, Wv, Wo, Wt);
    gemm_proj<<<gGemm, b256, 0, stream>>>(q, Wt + (size_t)0 * 1024 * 1024, QP, 0.125f * LOG2E, 0);
    gemm_proj<<<gGemm, b256, 0, stream>>>(k, Wt + (size_t)1 * 1024 * 1024, KP, 1.0f, 0);
    gemm_proj<<<gGemm, b256, 0, stream>>>(v, Wt + (size_t)2 * 1024 * 1024, VTb, 1.0f, 1);
    attn_kernel<<<dim3(8, 64), dim3(512), 0, stream>>>(QP, KP, VTb, maskAndB, AO);
    gemm_out<<<gGemm, b256, 0, stream>>>(AO, Wt + (size_t)3 * 1024 * 1024, out);
}